// Round 15
// baseline (574.328 us; speedup 1.0000x reference)
//
#include <hip/hip_runtime.h>
#include <hip/hip_fp16.h>

constexpr int NN   = 100000;
constexpr int EE   = 1600000;
constexpr int ETOT = EE + NN;
constexpr float SLOPE = 0.2f;
constexpr int BSH = 10;     // nodes per bucket = 1024
constexpr int NB  = (NN + (1 << BSH) - 1) >> BSH;  // 98 buckets
constexpr int CCH = 8192;   // edges per scatter block
constexpr int DCAP  = 36;   // per-node edge cap for packed path (P(Poisson(16)+1>36)~2e-7)
constexpr int DCAPP = 37;   // padded stride -> phase-B reads conflict-free (see R10)

typedef __attribute__((ext_vector_type(8))) short short8;
typedef __attribute__((ext_vector_type(4))) float f32x4;

__device__ __forceinline__ unsigned short f2h(float f) {
    __half h = __float2half(f);
    return *(unsigned short*)&h;
}
__device__ __forceinline__ float h_lo(unsigned u) {
    unsigned short s = u & 0xffff;
    return __half2float(*(__half*)&s);
}
__device__ __forceinline__ float h_hi(unsigned u) {
    unsigned short s = u >> 16;
    return __half2float(*(__half*)&s);
}
__device__ __forceinline__ void wave_lds_fence() {
    __asm__ volatile("s_waitcnt lgkmcnt(0)" ::: "memory");
}
__device__ __forceinline__ void pk8(__half2* acc2, uint4 u, __half2 a2) {
    acc2[0] = __hfma2(*(__half2*)&u.x, a2, acc2[0]);
    acc2[1] = __hfma2(*(__half2*)&u.y, a2, acc2[1]);
    acc2[2] = __hfma2(*(__half2*)&u.z, a2, acc2[2]);
    acc2[3] = __hfma2(*(__half2*)&u.w, a2, acc2[3]);
}
__device__ __forceinline__ void fma8f(float* acc, uint4 u, float al) {  // cold path
    acc[0] += h_lo(u.x) * al; acc[1] += h_hi(u.x) * al;
    acc[2] += h_lo(u.y) * al; acc[3] += h_hi(u.y) * al;
    acc[4] += h_lo(u.z) * al; acc[5] += h_hi(u.z) * al;
    acc[6] += h_lo(u.w) * al; acc[7] += h_hi(u.w) * al;
}

// ---------------- all-weights conversion in one launch ----------------
__global__ void k_cvt_w4(const float* __restrict__ W0, const float* __restrict__ W1,
                         const float* __restrict__ W2, const float* __restrict__ Wf,
                         unsigned short* __restrict__ Wt0, unsigned short* __restrict__ Wt1,
                         unsigned short* __restrict__ Wt2, unsigned short* __restrict__ Wtf) {
    int i = blockIdx.x * blockDim.x + threadIdx.x;
    if (i < 8192) { int k = i / 128, n = i % 128; Wt0[n * 64 + k] = f2h(W0[i]); return; }
    i -= 8192;
    if (i < 16384) { int k = i / 128, n = i % 128; Wt1[n * 128 + k] = f2h(W1[i]); return; }
    i -= 16384;
    if (i < 16384) { int k = i / 128, n = i % 128; Wt2[n * 128 + k] = f2h(W2[i]); return; }
    i -= 16384;
    if (i < 4096) { int k = i / 32, n = i % 32; Wtf[n * 128 + k] = f2h(Wf[i]); }
}

// ---------------- bucketed CSR build ----------------
__global__ void k_zero(int* p, int n) {
    int i = blockIdx.x * blockDim.x + threadIdx.x;
    if (i < n) p[i] = 0;
}

__global__ __launch_bounds__(256) void k_bhist(const int* __restrict__ ei,
                                               int* __restrict__ gbh) {
    __shared__ int h[NB];
    int t = threadIdx.x;
    if (t < NB) h[t] = 0;
    __syncthreads();
    int i = blockIdx.x * 2048 + t;
#pragma unroll
    for (int k = 0; k < 8; k++, i += 256)
        if (i < EE) atomicAdd(&h[ei[EE + i] >> BSH], 1);
    __syncthreads();
    if (t < NB && h[t]) atomicAdd(&gbh[t], h[t]);
}

__global__ void k_bscan(const int* __restrict__ gbh, int* __restrict__ ebase,
                        int* __restrict__ gcur) {
    __shared__ int sd[128];
    int t = threadIdx.x;
    int v = (t < NB) ? gbh[t] : 0;
    sd[t] = v;
    __syncthreads();
    for (int off = 1; off < 128; off <<= 1) {
        int x = (t >= off) ? sd[t - off] : 0;
        __syncthreads();
        sd[t] += x;
        __syncthreads();
    }
    int ex = sd[t] - v;
    if (t < NB) { ebase[t] = ex; gcur[t] = ex; }
    if (t == NB) ebase[NB] = EE;
}

__global__ __launch_bounds__(256) void k_bscatter(const int* __restrict__ ei,
                                                  int* __restrict__ gcur,
                                                  int* __restrict__ pbuf) {
    __shared__ int h[NB], base[NB], cur[NB];
    int t = threadIdx.x;
    if (t < NB) { h[t] = 0; cur[t] = 0; }
    __syncthreads();
    int c0 = blockIdx.x * CCH;
    int cend = c0 + CCH < EE ? c0 + CCH : EE;
    for (int i = c0 + t; i < cend; i += 256)
        atomicAdd(&h[ei[EE + i] >> BSH], 1);
    __syncthreads();
    if (t < NB && h[t] > 0) base[t] = atomicAdd(&gcur[t], h[t]);
    __syncthreads();
    for (int i = c0 + t; i < cend; i += 256) {
        int s = ei[i], d = ei[EE + i];
        int b = d >> BSH;
        int c = atomicAdd(&cur[b], 1);
        pbuf[base[b] + c] = s | ((d & ((1 << BSH) - 1)) << 17);
    }
}

__global__ __launch_bounds__(256) void k_bcsr(const int* __restrict__ pbuf,
                                              const int* __restrict__ ebase,
                                              int* __restrict__ row_ptr,
                                              int* __restrict__ esrc) {
    constexpr int BNODES = 1 << BSH;
    __shared__ int hist[BNODES];
    __shared__ int cur[BNODES];
    __shared__ int sd[256];
    int b = blockIdx.x, t = threadIdx.x;
    int node0 = b << BSH;
    int e0 = ebase[b], e1 = ebase[b + 1];
    for (int i = t; i < BNODES; i += 256) { hist[i] = 0; cur[i] = 0; }
    __syncthreads();
    for (int i = e0 + t; i < e1; i += 256)
        atomicAdd(&hist[pbuf[i] >> 17], 1);
    __syncthreads();
    int s0 = hist[4 * t], s1 = hist[4 * t + 1], s2 = hist[4 * t + 2], s3 = hist[4 * t + 3];
    int ts = s0 + s1 + s2 + s3;
    sd[t] = ts;
    __syncthreads();
    for (int off = 1; off < 256; off <<= 1) {
        int x = (t >= off) ? sd[t - off] : 0;
        __syncthreads();
        sd[t] += x;
        __syncthreads();
    }
    int ex = sd[t] - ts;
    hist[4 * t] = ex;
    hist[4 * t + 1] = ex + s0;
    hist[4 * t + 2] = ex + s0 + s1;
    hist[4 * t + 3] = ex + s0 + s1 + s2;
    __syncthreads();
    int rbase = e0 + node0;
    for (int nl = t; nl < BNODES; nl += 256) {
        int n = node0 + nl;
        if (n < NN) {
            int rp = rbase + hist[nl] + nl;
            row_ptr[n] = rp;
            esrc[rp] = n;  // self loop in slot 0
        }
    }
    __syncthreads();
    for (int i = e0 + t; i < e1; i += 256) {
        int p = pbuf[i];
        int nl = p >> 17;
        int c = atomicAdd(&cur[nl], 1);
        esrc[rbase + hist[nl] + nl + 1 + c] = p & 0x1FFFF;
    }
}

// -------- wave-per-node bitonic sort of each edge run (src-ascending) --------
// Makes every aggregation block sweep hb in ascending src order -> concurrently
// resident blocks stay temporally aligned, hot src window stays L2-resident
// (R13 evidence: ~43 us agg gain). deg>64 runs left unsorted (perf hint only).
__global__ __launch_bounds__(256) void k_sortruns(const int* __restrict__ row_ptr,
                                                  int* __restrict__ esrc) {
    int lane = threadIdx.x & 63;
    int n = blockIdx.x * 4 + (threadIdx.x >> 6);
    if (n >= NN) return;
    int start = row_ptr[n];
    int end = (n == NN - 1) ? ETOT : row_ptr[n + 1];
    int deg = end - start;
    if (deg > 64) return;  // cold, unsorted is fine
    unsigned v = (lane < deg) ? (unsigned)esrc[start + lane] : 0xFFFFFFFFu;
#pragma unroll
    for (int k = 2; k <= 64; k <<= 1) {
#pragma unroll
        for (int j = k >> 1; j >= 1; j >>= 1) {
            unsigned o = __shfl_xor(v, j);
            bool take_min = (((lane & j) == 0) == ((lane & k) == 0));
            v = take_min ? min(v, o) : max(v, o);
        }
    }
    if (lane < deg) esrc[start + lane] = (int)v;
}

// ------- f16 MFMA GEMM (128xBN tile) + fused att dots + f16 h (R12 epilogue) -------
template <int BN, int H, bool AF32>
__global__ __launch_bounds__(256) void k_mfma_att(
    const void* __restrict__ Aptr, const unsigned short* __restrict__ Bt,
    const float* __restrict__ as_, const float* __restrict__ ad_,
    unsigned short* __restrict__ hb, float* __restrict__ a_s,
    float* __restrict__ a_d, int M, int K) {
    constexpr int NCT = BN / 16;
    constexpr int LDK = 72;  // 64-slab + 8-short pad
    __shared__ unsigned short As[128 * LDK];
    __shared__ unsigned short Bs[BN * LDK];
    int tid = threadIdx.x;
    int lane = tid & 63, w = tid >> 6;
    int q = lane >> 4, col = lane & 15;
    int rowBase = blockIdx.x * 128;

    f32x4 acc[2][NCT];
#pragma unroll
    for (int rt = 0; rt < 2; rt++)
#pragma unroll
        for (int ct = 0; ct < NCT; ct++) acc[rt][ct] = (f32x4){0.f, 0.f, 0.f, 0.f};

    int u = tid & 7;
    int r0 = tid >> 3;
    int nph = K >> 6;
    for (int ph = 0; ph < nph; ph++) {
        int kof = ph * 64 + u * 8;
#pragma unroll
        for (int rr = r0; rr < 128; rr += 32) {
            int gr = rowBase + rr;
            if constexpr (AF32) {
                const float* A = (const float*)Aptr;
                unsigned short o[8] = {0, 0, 0, 0, 0, 0, 0, 0};
                if (gr < M) {
                    const float4* ap = (const float4*)(A + (size_t)gr * K + kof);
                    float4 v0 = ap[0], v1 = ap[1];
                    o[0] = f2h(v0.x); o[1] = f2h(v0.y); o[2] = f2h(v0.z); o[3] = f2h(v0.w);
                    o[4] = f2h(v1.x); o[5] = f2h(v1.y); o[6] = f2h(v1.z); o[7] = f2h(v1.w);
                }
                *(uint4*)(&As[rr * LDK + u * 8]) = *(uint4*)o;
            } else {
                const unsigned short* A = (const unsigned short*)Aptr;
                uint4 v = make_uint4(0, 0, 0, 0);
                if (gr < M) v = *(const uint4*)(A + (size_t)gr * K + kof);
                *(uint4*)(&As[rr * LDK + u * 8]) = v;
            }
        }
#pragma unroll
        for (int br = r0; br < BN; br += 32) {
            uint4 v = *(const uint4*)(Bt + (size_t)br * K + kof);
            *(uint4*)(&Bs[br * LDK + u * 8]) = v;
        }
        __syncthreads();

        short8 af[2][2];
#pragma unroll
        for (int rt = 0; rt < 2; rt++)
#pragma unroll
            for (int kt = 0; kt < 2; kt++)
                af[rt][kt] = *(const short8*)(&As[(w * 32 + rt * 16 + col) * LDK + kt * 32 + q * 8]);
#pragma unroll
        for (int kt = 0; kt < 2; kt++)
#pragma unroll
            for (int ct = 0; ct < NCT; ct++) {
                short8 bf = *(const short8*)(&Bs[(ct * 16 + col) * LDK + kt * 32 + q * 8]);
#pragma unroll
                for (int rt = 0; rt < 2; rt++)
                    acc[rt][ct] = __builtin_amdgcn_mfma_f32_16x16x32_f16(
                        af[rt][kt], bf, acc[rt][ct], 0, 0, 0);
            }
        __syncthreads();
    }

    float swv[NCT], dwv[NCT];
#pragma unroll
    for (int ct = 0; ct < NCT; ct++) {
        int c = ct * 16 + col;
        swv[ct] = as_[c];
        dwv[ct] = ad_[c];
    }
#pragma unroll
    for (int rt = 0; rt < 2; rt++) {
#pragma unroll
        for (int r = 0; r < 4; r++) {
            int gr = rowBase + w * 32 + rt * 16 + q * 4 + r;
            if constexpr (H == 4) {
                float ps[4] = {0, 0, 0, 0}, pd[4] = {0, 0, 0, 0};
#pragma unroll
                for (int ct = 0; ct < NCT; ct++) {
                    float v = acc[rt][ct][r];
                    ps[ct >> 1] += v * swv[ct];
                    pd[ct >> 1] += v * dwv[ct];
                }
#pragma unroll
                for (int m = 1; m < 16; m <<= 1)
#pragma unroll
                    for (int h = 0; h < 4; h++) {
                        ps[h] += __shfl_xor(ps[h], m);
                        pd[h] += __shfl_xor(pd[h], m);
                    }
                if (gr < M) {
#pragma unroll
                    for (int ct = 0; ct < NCT; ct++)
                        hb[(size_t)gr * BN + ct * 16 + col] = f2h(acc[rt][ct][r]);
                    if (col == 0) {
                        *(float4*)(a_s + (size_t)gr * 4) = make_float4(ps[0], ps[1], ps[2], ps[3]);
                        *(float4*)(a_d + (size_t)gr * 4) = make_float4(pd[0], pd[1], pd[2], pd[3]);
                    }
                }
            } else {
                float ps = 0.f, pd = 0.f;
#pragma unroll
                for (int ct = 0; ct < NCT; ct++) {
                    float v = acc[rt][ct][r];
                    ps += v * swv[ct];
                    pd += v * dwv[ct];
                }
#pragma unroll
                for (int m = 1; m < 16; m <<= 1) {
                    ps += __shfl_xor(ps, m);
                    pd += __shfl_xor(pd, m);
                }
                if (gr < M) {
#pragma unroll
                    for (int ct = 0; ct < NCT; ct++)
                        hb[(size_t)gr * BN + ct * 16 + col] = f2h(acc[rt][ct][r]);
                    if (col == 0) { a_s[gr] = ps; a_d[gr] = pd; }
                }
            }
        }
    }
}

// -------- 4-nodes-per-wave: softmax + aggregate(f16 h, pk_fma) + bias + LN + ELU --------
__global__ __launch_bounds__(256) void k_aggregate_ln(
    const unsigned short* __restrict__ hb, const float* __restrict__ a_src,
    const float* __restrict__ a_dst, const int* __restrict__ row_ptr,
    const int* __restrict__ esrc, const float* __restrict__ bias,
    const float* __restrict__ gamma, const float* __restrict__ beta,
    unsigned short* __restrict__ xb) {
    __shared__ uint2 slab_all[4][4 * 4 * DCAPP];  // [wave][node][head][j]
    int tid = threadIdx.x;
    int w = tid >> 6, lane = tid & 63;
    int g = lane >> 4, i = lane & 15;
    int myhead = i >> 2;
    uint2* slab = slab_all[w];
    int n0 = blockIdx.x * 16 + w * 4;
    int n = n0 + g;
    bool valid = n < NN;
    int start = 0, deg = 0;
    if (valid) {
        start = row_ptr[n];
        int end = (n == NN - 1) ? ETOT : row_ptr[n + 1];
        deg = end - start;
    }
    int wmax = deg;
#pragma unroll
    for (int m = 1; m < 64; m <<= 1) wmax = max(wmax, __shfl_xor(wmax, m));

    if (wmax <= DCAP) {
        float4 ad = make_float4(0.f, 0.f, 0.f, 0.f);
        if (valid) ad = ((const float4*)a_dst)[n];
        float d0 = 0.f, d1 = 0.f, d2 = 0.f, d3 = 0.f;
        uint2* nslab = slab + g * (4 * DCAPP);
        for (int k = i; k < deg; k += 16) {
            int s = esrc[start + k];
            float4 a = ((const float4*)a_src)[s];
            float e0 = a.x + ad.x; e0 = fmaxf(e0, SLOPE * e0); float x0 = __expf(e0);
            float e1 = a.y + ad.y; e1 = fmaxf(e1, SLOPE * e1); float x1 = __expf(e1);
            float e2 = a.z + ad.z; e2 = fmaxf(e2, SLOPE * e2); float x2 = __expf(e2);
            float e3 = a.w + ad.w; e3 = fmaxf(e3, SLOPE * e3); float x3 = __expf(e3);
            nslab[0 * DCAPP + k] = make_uint2((unsigned)s, __float_as_uint(x0));
            nslab[1 * DCAPP + k] = make_uint2((unsigned)s, __float_as_uint(x1));
            nslab[2 * DCAPP + k] = make_uint2((unsigned)s, __float_as_uint(x2));
            nslab[3 * DCAPP + k] = make_uint2((unsigned)s, __float_as_uint(x3));
            d0 += x0; d1 += x1; d2 += x2; d3 += x3;
        }
#pragma unroll
        for (int m = 1; m < 16; m <<= 1) {
            d0 += __shfl_xor(d0, m);
            d1 += __shfl_xor(d1, m);
            d2 += __shfl_xor(d2, m);
            d3 += __shfl_xor(d3, m);
        }
        float dh = myhead == 0 ? d0 : myhead == 1 ? d1 : myhead == 2 ? d2 : d3;
        float inv = 1.f / (dh + 1e-16f);
        wave_lds_fence();

        __half2 acc2[4];
#pragma unroll
        for (int k = 0; k < 4; k++) acc2[k] = __float2half2_rn(0.f);
        const uint2* myrow = nslab + myhead * DCAPP;
        const unsigned short* hbase = hb + i * 8;
        int j = 0;
        for (; j + 4 <= deg; j += 4) {
            uint2 p0 = myrow[j], p1 = myrow[j + 1], p2 = myrow[j + 2], p3 = myrow[j + 3];
            uint4 u0 = *(const uint4*)(hbase + (size_t)p0.x * 128);
            uint4 u1 = *(const uint4*)(hbase + (size_t)p1.x * 128);
            uint4 u2 = *(const uint4*)(hbase + (size_t)p2.x * 128);
            uint4 u3 = *(const uint4*)(hbase + (size_t)p3.x * 128);
            pk8(acc2, u0, __float2half2_rn(__uint_as_float(p0.y)));
            pk8(acc2, u1, __float2half2_rn(__uint_as_float(p1.y)));
            pk8(acc2, u2, __float2half2_rn(__uint_as_float(p2.y)));
            pk8(acc2, u3, __float2half2_rn(__uint_as_float(p3.y)));
        }
        for (; j < deg; j++) {
            uint2 p = myrow[j];
            uint4 uu = *(const uint4*)(hbase + (size_t)p.x * 128);
            pk8(acc2, uu, __float2half2_rn(__uint_as_float(p.y)));
        }
        float acc[8];
#pragma unroll
        for (int k = 0; k < 4; k++) {
            float2 f = __half22float2(acc2[k]);
            acc[2 * k] = f.x * inv;
            acc[2 * k + 1] = f.y * inv;
        }

        if (valid) {
            float y[8];
            float sum = 0.f;
            const float4* bp = (const float4*)(bias + i * 8);
            float4 b0 = bp[0], b1 = bp[1];
#pragma unroll
            for (int k = 0; k < 8; k++) {
                float b = k < 4 ? (&b0.x)[k] : (&b1.x)[k - 4];
                y[k] = acc[k] + b;
                sum += y[k];
            }
#pragma unroll
            for (int m = 1; m < 16; m <<= 1) sum += __shfl_xor(sum, m);
            float mu = sum * (1.f / 128.f);
            float ss = 0.f;
            float d[8];
#pragma unroll
            for (int k = 0; k < 8; k++) { d[k] = y[k] - mu; ss += d[k] * d[k]; }
#pragma unroll
            for (int m = 1; m < 16; m <<= 1) ss += __shfl_xor(ss, m);
            float is = rsqrtf(ss * (1.f / 128.f) + 1e-5f);
            const float4* gp = (const float4*)(gamma + i * 8);
            const float4* ep = (const float4*)(beta + i * 8);
            float4 g0 = gp[0], g1 = gp[1], e0 = ep[0], e1 = ep[1];
            unsigned short o16[8];
#pragma unroll
            for (int k = 0; k < 8; k++) {
                float gm = k < 4 ? (&g0.x)[k] : (&g1.x)[k - 4];
                float bt = k < 4 ? (&e0.x)[k] : (&e1.x)[k - 4];
                float z = gm * (d[k] * is) + bt;
                o16[k] = f2h(z > 0.f ? z : __expf(z) - 1.f);
            }
            *(uint4*)(xb + (size_t)n * 128 + i * 8) = *(uint4*)o16;
        }
    } else {
        // cold path (~never): full-wave sequential, f32 accumulate
        for (int m4 = 0; m4 < 4; m4++) {
            int nm = n0 + m4;
            if (nm >= NN) continue;
            int startm = row_ptr[nm];
            int endm = (nm == NN - 1) ? ETOT : row_ptr[nm + 1];
            int degm = endm - startm;
            float4 ad = ((const float4*)a_dst)[nm];
            int gg = lane >> 4, c16 = lane & 15, hh = c16 >> 2;
            float acc[8];
#pragma unroll
            for (int k = 0; k < 8; k++) acc[k] = 0.f;
            if (degm <= 64) {
                int msrc = 0;
                float me0 = 0.f, me1 = 0.f, me2 = 0.f, me3 = 0.f;
                if (lane < degm) {
                    int s = esrc[startm + lane];
                    msrc = s;
                    float4 a = ((const float4*)a_src)[s];
                    float e0 = a.x + ad.x; e0 = fmaxf(e0, SLOPE * e0); me0 = __expf(e0);
                    float e1 = a.y + ad.y; e1 = fmaxf(e1, SLOPE * e1); me1 = __expf(e1);
                    float e2 = a.z + ad.z; e2 = fmaxf(e2, SLOPE * e2); me2 = __expf(e2);
                    float e3 = a.w + ad.w; e3 = fmaxf(e3, SLOPE * e3); me3 = __expf(e3);
                }
                float d0 = me0, d1 = me1, d2 = me2, d3 = me3;
#pragma unroll
                for (int m = 1; m < 64; m <<= 1) {
                    d0 += __shfl_xor(d0, m);
                    d1 += __shfl_xor(d1, m);
                    d2 += __shfl_xor(d2, m);
                    d3 += __shfl_xor(d3, m);
                }
                me0 *= 1.f / (d0 + 1e-16f);
                me1 *= 1.f / (d1 + 1e-16f);
                me2 *= 1.f / (d2 + 1e-16f);
                me3 *= 1.f / (d3 + 1e-16f);
                int iters = (degm + 3) >> 2;
                for (int it = 0; it < iters; it++) {
                    int j = gg + (it << 2);
                    int jj = j < degm ? j : 0;
                    int s = __shfl(msrc, jj);
                    float a0 = __shfl(me0, jj), a1 = __shfl(me1, jj);
                    float a2 = __shfl(me2, jj), a3 = __shfl(me3, jj);
                    if (j < degm) {
                        float al = hh == 0 ? a0 : hh == 1 ? a1 : hh == 2 ? a2 : a3;
                        uint4 uu = *(const uint4*)(hb + (size_t)s * 128 + c16 * 8);
                        fma8f(acc, uu, al);
                    }
                }
            } else {
                float d0 = 0.f, d1 = 0.f, d2 = 0.f, d3 = 0.f;
                for (int k = startm + lane; k < endm; k += 64) {
                    int s = esrc[k];
                    float4 a = ((const float4*)a_src)[s];
                    float e0 = a.x + ad.x; e0 = fmaxf(e0, SLOPE * e0); d0 += __expf(e0);
                    float e1 = a.y + ad.y; e1 = fmaxf(e1, SLOPE * e1); d1 += __expf(e1);
                    float e2 = a.z + ad.z; e2 = fmaxf(e2, SLOPE * e2); d2 += __expf(e2);
                    float e3 = a.w + ad.w; e3 = fmaxf(e3, SLOPE * e3); d3 += __expf(e3);
                }
#pragma unroll
                for (int m = 1; m < 64; m <<= 1) {
                    d0 += __shfl_xor(d0, m);
                    d1 += __shfl_xor(d1, m);
                    d2 += __shfl_xor(d2, m);
                    d3 += __shfl_xor(d3, m);
                }
                float invh = hh == 0 ? 1.f / (d0 + 1e-16f) : hh == 1 ? 1.f / (d1 + 1e-16f)
                           : hh == 2 ? 1.f / (d2 + 1e-16f) : 1.f / (d3 + 1e-16f);
                float adh = hh == 0 ? ad.x : hh == 1 ? ad.y : hh == 2 ? ad.z : ad.w;
                for (int j = gg; j < degm; j += 4) {
                    int s = esrc[startm + j];
                    float e = a_src[(size_t)s * 4 + hh] + adh;
                    e = fmaxf(e, SLOPE * e);
                    float al = __expf(e) * invh;
                    uint4 uu = *(const uint4*)(hb + (size_t)s * 128 + c16 * 8);
                    fma8f(acc, uu, al);
                }
            }
#pragma unroll
            for (int k = 0; k < 8; k++) {
                acc[k] += __shfl_xor(acc[k], 16);
                acc[k] += __shfl_xor(acc[k], 32);
            }
            if (lane < 16) {
                float y[8];
                float sum = 0.f;
                const float4* bp = (const float4*)(bias + lane * 8);
                float4 b0 = bp[0], b1 = bp[1];
#pragma unroll
                for (int k = 0; k < 8; k++) {
                    float b = k < 4 ? (&b0.x)[k] : (&b1.x)[k - 4];
                    y[k] = acc[k] + b;
                    sum += y[k];
                }
#pragma unroll
                for (int m = 1; m < 16; m <<= 1) sum += __shfl_xor(sum, m);
                float mu = sum * (1.f / 128.f);
                float ss = 0.f;
                float d[8];
#pragma unroll
                for (int k = 0; k < 8; k++) { d[k] = y[k] - mu; ss += d[k] * d[k]; }
#pragma unroll
                for (int m = 1; m < 16; m <<= 1) ss += __shfl_xor(ss, m);
                float is = rsqrtf(ss * (1.f / 128.f) + 1e-5f);
                const float4* gp = (const float4*)(gamma + lane * 8);
                const float4* ep = (const float4*)(beta + lane * 8);
                float4 g0 = gp[0], g1 = gp[1], e0 = ep[0], e1 = ep[1];
                unsigned short o16[8];
#pragma unroll
                for (int k = 0; k < 8; k++) {
                    float gm = k < 4 ? (&g0.x)[k] : (&g1.x)[k - 4];
                    float bt = k < 4 ? (&e0.x)[k] : (&e1.x)[k - 4];
                    float z = gm * (d[k] * is) + bt;
                    o16[k] = f2h(z > 0.f ? z : __expf(z) - 1.f);
                }
                *(uint4*)(xb + (size_t)nm * 128 + lane * 8) = *(uint4*)o16;
            }
        }
    }
}

// -------- final layer, wave-per-node: H=1, C=32 (f16 h), writes fp32 d_out --------
__global__ __launch_bounds__(256) void k_agg_final(
    const unsigned short* __restrict__ hb, const float* __restrict__ a_src,
    const float* __restrict__ a_dst, const int* __restrict__ row_ptr,
    const int* __restrict__ esrc, const float* __restrict__ bf,
    float* __restrict__ out) {
    __shared__ uint2 slab_all[4][64];
    int lane = threadIdx.x & 63;
    int w = threadIdx.x >> 6;
    uint2* slab = slab_all[w];
    int n = blockIdx.x * 4 + w;
    if (n >= NN) return;
    int start = row_ptr[n];
    int end = (n == NN - 1) ? ETOT : row_ptr[n + 1];
    int deg = end - start;
    float adn = a_dst[n];

    int g = lane >> 3, c8 = lane & 7;
    float acc[4] = {0.f, 0.f, 0.f, 0.f};

    if (deg <= 64) {
        int msrc = 0;
        float me = 0.f;
        if (lane < deg) {
            int s = esrc[start + lane];
            msrc = s;
            float e = a_src[s] + adn;
            e = fmaxf(e, SLOPE * e);
            me = __expf(e);
        }
        float d = me;
#pragma unroll
        for (int m = 1; m < 64; m <<= 1) d += __shfl_xor(d, m);
        float inv = 1.f / (d + 1e-16f);
        if (lane < deg) slab[lane] = make_uint2((unsigned)msrc, __float_as_uint(me));
        wave_lds_fence();
        __half2 acc2[2] = {__float2half2_rn(0.f), __float2half2_rn(0.f)};
        const unsigned short* hbase = hb + c8 * 4;
        int j = g;
        for (; j + 8 < deg; j += 16) {
            uint2 p0 = slab[j], p1 = slab[j + 8];
            uint2 u0 = *(const uint2*)(hbase + (size_t)p0.x * 32);
            uint2 u1 = *(const uint2*)(hbase + (size_t)p1.x * 32);
            __half2 a0 = __float2half2_rn(__uint_as_float(p0.y));
            __half2 a1 = __float2half2_rn(__uint_as_float(p1.y));
            acc2[0] = __hfma2(*(__half2*)&u0.x, a0, acc2[0]);
            acc2[1] = __hfma2(*(__half2*)&u0.y, a0, acc2[1]);
            acc2[0] = __hfma2(*(__half2*)&u1.x, a1, acc2[0]);
            acc2[1] = __hfma2(*(__half2*)&u1.y, a1, acc2[1]);
        }
        if (j < deg) {
            uint2 p = slab[j];
            uint2 u = *(const uint2*)(hbase + (size_t)p.x * 32);
            __half2 a2 = __float2half2_rn(__uint_as_float(p.y));
            acc2[0] = __hfma2(*(__half2*)&u.x, a2, acc2[0]);
            acc2[1] = __hfma2(*(__half2*)&u.y, a2, acc2[1]);
        }
        float2 f0 = __half22float2(acc2[0]);
        float2 f1 = __half22float2(acc2[1]);
        acc[0] = f0.x * inv; acc[1] = f0.y * inv;
        acc[2] = f1.x * inv; acc[3] = f1.y * inv;
    } else {
        float d = 0.f;
        for (int k = start + lane; k < end; k += 64) {
            int s = esrc[k];
            float e = a_src[s] + adn;
            e = fmaxf(e, SLOPE * e);
            d += __expf(e);
        }
#pragma unroll
        for (int m = 1; m < 64; m <<= 1) d += __shfl_xor(d, m);
        float inv = 1.f / (d + 1e-16f);
        for (int j = g; j < deg; j += 8) {
            int s = esrc[start + j];
            float e = a_src[s] + adn;
            e = fmaxf(e, SLOPE * e);
            float al = __expf(e) * inv;
            uint2 u = *(const uint2*)(hb + (size_t)s * 32 + c8 * 4);
            acc[0] += h_lo(u.x) * al; acc[1] += h_hi(u.x) * al;
            acc[2] += h_lo(u.y) * al; acc[3] += h_hi(u.y) * al;
        }
    }
#pragma unroll
    for (int k = 0; k < 4; k++) {
        acc[k] += __shfl_xor(acc[k], 8);
        acc[k] += __shfl_xor(acc[k], 16);
        acc[k] += __shfl_xor(acc[k], 32);
    }
    if (lane < 8) {
        float4 b4 = ((const float4*)bf)[lane];
        float4 o = make_float4(acc[0] + b4.x, acc[1] + b4.y, acc[2] + b4.z,
                               acc[3] + b4.w);
        ((float4*)out)[(size_t)n * 8 + lane] = o;
    }
}

// ---------------- launch ----------------
extern "C" void kernel_launch(void* const* d_in, const int* in_sizes, int n_in,
                              void* d_out, int out_size, void* d_ws,
                              size_t ws_size, hipStream_t stream) {
    const float* x  = (const float*)d_in[0];
    const int* ei   = (const int*)d_in[1];
    const float* W[3]  = {(const float*)d_in[2], (const float*)d_in[8],  (const float*)d_in[14]};
    const float* AS[3] = {(const float*)d_in[3], (const float*)d_in[9],  (const float*)d_in[15]};
    const float* AD[3] = {(const float*)d_in[4], (const float*)d_in[10], (const float*)d_in[16]};
    const float* Bb[3] = {(const float*)d_in[5], (const float*)d_in[11], (const float*)d_in[17]};
    const float* G[3]  = {(const float*)d_in[6], (const float*)d_in[12], (const float*)d_in[18]};
    const float* BE[3] = {(const float*)d_in[7], (const float*)d_in[13], (const float*)d_in[19]};
    const float* Wf  = (const float*)d_in[20];
    const float* asf = (const float*)d_in[21];
    const float* adf = (const float*)d_in[22];
    const float* bfp = (const float*)d_in[23];
    float* out = (float*)d_out;

    unsigned short* xb = (unsigned short*)d_ws;          // NN*128 f16 (agg outputs)
    unsigned short* hb = xb + (size_t)NN * 128;          // NN*128 f16
    float* a_s = (float*)(hb + (size_t)NN * 128);
    float* a_d = a_s + (size_t)NN * 4;
    int* row_ptr = (int*)(a_d + (size_t)NN * 4);
    int* esrc    = row_ptr + NN;
    int* gbh     = esrc + ETOT;
    int* ebase   = gbh + NB;
    int* gcur    = ebase + NB + 1;
    int* pbuf    = gcur + NB;                            // EE ints
    unsigned short* Wt0 = (unsigned short*)(pbuf + EE);  // 128*64
    unsigned short* Wt1 = Wt0 + 128 * 64;                // 128*128
    unsigned short* Wt2 = Wt1 + 128 * 128;               // 128*128
    unsigned short* Wtf = Wt2 + 128 * 128;               // 32*128

    // weights conversion (single launch)
    k_cvt_w4<<<(45056 + 255) / 256, 256, 0, stream>>>(W[0], W[1], W[2], Wf,
                                                      Wt0, Wt1, Wt2, Wtf);

    // CSR build + per-node src-sort (wave bitonic)
    k_zero<<<1, 128, 0, stream>>>(gbh, NB);
    k_bhist<<<(EE + 2047) / 2048, 256, 0, stream>>>(ei, gbh);
    k_bscan<<<1, 128, 0, stream>>>(gbh, ebase, gcur);
    k_bscatter<<<(EE + CCH - 1) / CCH, 256, 0, stream>>>(ei, gcur, pbuf);
    k_bcsr<<<NB, 256, 0, stream>>>(pbuf, ebase, row_ptr, esrc);
    k_sortruns<<<(NN + 3) / 4, 256, 0, stream>>>(row_ptr, esrc);

    // layers (layer 0 reads fp32 x directly)
    int gblk = (NN + 127) / 128;
    k_mfma_att<128, 4, true><<<gblk, 256, 0, stream>>>(x, Wt0, AS[0], AD[0],
                                                       hb, a_s, a_d, NN, 64);
    k_aggregate_ln<<<(NN + 15) / 16, 256, 0, stream>>>(hb, a_s, a_d, row_ptr,
                                                       esrc, Bb[0], G[0], BE[0], xb);
    const unsigned short* Wts[2] = {Wt1, Wt2};
    for (int l = 1; l < 3; l++) {
        k_mfma_att<128, 4, false><<<gblk, 256, 0, stream>>>(xb, Wts[l - 1], AS[l], AD[l],
                                                            hb, a_s, a_d, NN, 128);
        k_aggregate_ln<<<(NN + 15) / 16, 256, 0, stream>>>(hb, a_s, a_d, row_ptr,
                                                           esrc, Bb[l], G[l], BE[l], xb);
    }
    k_mfma_att<32, 1, false><<<gblk, 256, 0, stream>>>(xb, Wtf, asf, adf, hb, a_s, a_d,
                                                       NN, 128);
    k_agg_final<<<(NN + 3) / 4, 256, 0, stream>>>(hb, a_s, a_d, row_ptr, esrc,
                                                  bfp, out);
}

// Round 16
// 547.766 us; speedup vs baseline: 1.0485x; 1.0485x over previous
//
#include <hip/hip_runtime.h>
#include <hip/hip_fp16.h>

constexpr int NN   = 100000;
constexpr int EE   = 1600000;
constexpr int ETOT = EE + NN;
constexpr float SLOPE = 0.2f;
constexpr int BSH = 10;     // nodes per bucket = 1024
constexpr int NB  = (NN + (1 << BSH) - 1) >> BSH;  // 98 buckets
constexpr int CCH = 8192;   // edges per scatter block
constexpr int DCAP  = 36;   // per-node edge cap for packed path (P(Poisson(16)+1>36)~2e-7)
constexpr int DCAPP = 37;   // padded stride -> phase-B reads conflict-free (see R10)

typedef __attribute__((ext_vector_type(8))) short short8;
typedef __attribute__((ext_vector_type(4))) float f32x4;

__device__ __forceinline__ unsigned short f2h(float f) {
    __half h = __float2half(f);
    return *(unsigned short*)&h;
}
__device__ __forceinline__ float h_lo(unsigned u) {
    unsigned short s = u & 0xffff;
    return __half2float(*(__half*)&s);
}
__device__ __forceinline__ float h_hi(unsigned u) {
    unsigned short s = u >> 16;
    return __half2float(*(__half*)&s);
}
__device__ __forceinline__ void wave_lds_fence() {
    __asm__ volatile("s_waitcnt lgkmcnt(0)" ::: "memory");
}
__device__ __forceinline__ void pk8(__half2* acc2, uint4 u, __half2 a2) {
    acc2[0] = __hfma2(*(__half2*)&u.x, a2, acc2[0]);
    acc2[1] = __hfma2(*(__half2*)&u.y, a2, acc2[1]);
    acc2[2] = __hfma2(*(__half2*)&u.z, a2, acc2[2]);
    acc2[3] = __hfma2(*(__half2*)&u.w, a2, acc2[3]);
}
__device__ __forceinline__ void fma8f(float* acc, uint4 u, float al) {  // cold path
    acc[0] += h_lo(u.x) * al; acc[1] += h_hi(u.x) * al;
    acc[2] += h_lo(u.y) * al; acc[3] += h_hi(u.y) * al;
    acc[4] += h_lo(u.z) * al; acc[5] += h_hi(u.z) * al;
    acc[6] += h_lo(u.w) * al; acc[7] += h_hi(u.w) * al;
}

// ---------------- all-weights conversion in one launch ----------------
__global__ void k_cvt_w4(const float* __restrict__ W0, const float* __restrict__ W1,
                         const float* __restrict__ W2, const float* __restrict__ Wf,
                         unsigned short* __restrict__ Wt0, unsigned short* __restrict__ Wt1,
                         unsigned short* __restrict__ Wt2, unsigned short* __restrict__ Wtf) {
    int i = blockIdx.x * blockDim.x + threadIdx.x;
    if (i < 8192) { int k = i / 128, n = i % 128; Wt0[n * 64 + k] = f2h(W0[i]); return; }
    i -= 8192;
    if (i < 16384) { int k = i / 128, n = i % 128; Wt1[n * 128 + k] = f2h(W1[i]); return; }
    i -= 16384;
    if (i < 16384) { int k = i / 128, n = i % 128; Wt2[n * 128 + k] = f2h(W2[i]); return; }
    i -= 16384;
    if (i < 4096) { int k = i / 32, n = i % 32; Wtf[n * 128 + k] = f2h(Wf[i]); }
}

// ---------------- bucketed CSR build ----------------
__global__ __launch_bounds__(256) void k_bhist(const int* __restrict__ ei,
                                               int* __restrict__ gbh) {
    __shared__ int h[NB];
    int t = threadIdx.x;
    if (t < NB) h[t] = 0;
    __syncthreads();
    int i = blockIdx.x * 2048 + t;
#pragma unroll
    for (int k = 0; k < 8; k++, i += 256)
        if (i < EE) atomicAdd(&h[ei[EE + i] >> BSH], 1);
    __syncthreads();
    if (t < NB && h[t]) atomicAdd(&gbh[t], h[t]);
}

__global__ void k_bscan(const int* __restrict__ gbh, int* __restrict__ ebase,
                        int* __restrict__ gcur) {
    __shared__ int sd[128];
    int t = threadIdx.x;
    int v = (t < NB) ? gbh[t] : 0;
    sd[t] = v;
    __syncthreads();
    for (int off = 1; off < 128; off <<= 1) {
        int x = (t >= off) ? sd[t - off] : 0;
        __syncthreads();
        sd[t] += x;
        __syncthreads();
    }
    int ex = sd[t] - v;
    if (t < NB) { ebase[t] = ex; gcur[t] = ex; }
    if (t == NB) ebase[NB] = EE;
}

__global__ __launch_bounds__(256) void k_bscatter(const int* __restrict__ ei,
                                                  int* __restrict__ gcur,
                                                  int* __restrict__ pbuf) {
    __shared__ int h[NB], base[NB], cur[NB];
    int t = threadIdx.x;
    if (t < NB) { h[t] = 0; cur[t] = 0; }
    __syncthreads();
    int c0 = blockIdx.x * CCH;
    int cend = c0 + CCH < EE ? c0 + CCH : EE;
    for (int i = c0 + t; i < cend; i += 256)
        atomicAdd(&h[ei[EE + i] >> BSH], 1);
    __syncthreads();
    if (t < NB && h[t] > 0) base[t] = atomicAdd(&gcur[t], h[t]);
    __syncthreads();
    for (int i = c0 + t; i < cend; i += 256) {
        int s = ei[i], d = ei[EE + i];
        int b = d >> BSH;
        int c = atomicAdd(&cur[b], 1);
        pbuf[base[b] + c] = s | ((d & ((1 << BSH) - 1)) << 17);
    }
}

__global__ __launch_bounds__(256) void k_bcsr(const int* __restrict__ pbuf,
                                              const int* __restrict__ ebase,
                                              int* __restrict__ row_ptr,
                                              int* __restrict__ esrc) {
    constexpr int BNODES = 1 << BSH;
    __shared__ int hist[BNODES];
    __shared__ int cur[BNODES];
    __shared__ int sd[256];
    int b = blockIdx.x, t = threadIdx.x;
    int node0 = b << BSH;
    int e0 = ebase[b], e1 = ebase[b + 1];
    for (int i = t; i < BNODES; i += 256) { hist[i] = 0; cur[i] = 0; }
    __syncthreads();
    for (int i = e0 + t; i < e1; i += 256)
        atomicAdd(&hist[pbuf[i] >> 17], 1);
    __syncthreads();
    int s0 = hist[4 * t], s1 = hist[4 * t + 1], s2 = hist[4 * t + 2], s3 = hist[4 * t + 3];
    int ts = s0 + s1 + s2 + s3;
    sd[t] = ts;
    __syncthreads();
    for (int off = 1; off < 256; off <<= 1) {
        int x = (t >= off) ? sd[t - off] : 0;
        __syncthreads();
        sd[t] += x;
        __syncthreads();
    }
    int ex = sd[t] - ts;
    hist[4 * t] = ex;
    hist[4 * t + 1] = ex + s0;
    hist[4 * t + 2] = ex + s0 + s1;
    hist[4 * t + 3] = ex + s0 + s1 + s2;
    __syncthreads();
    int rbase = e0 + node0;
    for (int nl = t; nl < BNODES; nl += 256) {
        int n = node0 + nl;
        if (n < NN) {
            int rp = rbase + hist[nl] + nl;
            row_ptr[n] = rp;
            esrc[rp] = n;  // self loop in slot 0
        }
    }
    __syncthreads();
    for (int i = e0 + t; i < e1; i += 256) {
        int p = pbuf[i];
        int nl = p >> 17;
        int c = atomicAdd(&cur[nl], 1);
        esrc[rbase + hist[nl] + nl + 1 + c] = p & 0x1FFFF;
    }
}

// ------- f16 MFMA GEMM (128xBN tile) + fused att dots + f16 h (R12 epilogue) -------
template <int BN, int H, bool AF32>
__global__ __launch_bounds__(256) void k_mfma_att(
    const void* __restrict__ Aptr, const unsigned short* __restrict__ Bt,
    const float* __restrict__ as_, const float* __restrict__ ad_,
    unsigned short* __restrict__ hb, float* __restrict__ a_s,
    float* __restrict__ a_d, int M, int K) {
    constexpr int NCT = BN / 16;
    constexpr int LDK = 72;  // 64-slab + 8-short pad
    __shared__ unsigned short As[128 * LDK];
    __shared__ unsigned short Bs[BN * LDK];
    int tid = threadIdx.x;
    int lane = tid & 63, w = tid >> 6;
    int q = lane >> 4, col = lane & 15;
    int rowBase = blockIdx.x * 128;

    f32x4 acc[2][NCT];
#pragma unroll
    for (int rt = 0; rt < 2; rt++)
#pragma unroll
        for (int ct = 0; ct < NCT; ct++) acc[rt][ct] = (f32x4){0.f, 0.f, 0.f, 0.f};

    int u = tid & 7;
    int r0 = tid >> 3;
    int nph = K >> 6;
    for (int ph = 0; ph < nph; ph++) {
        int kof = ph * 64 + u * 8;
#pragma unroll
        for (int rr = r0; rr < 128; rr += 32) {
            int gr = rowBase + rr;
            if constexpr (AF32) {
                const float* A = (const float*)Aptr;
                unsigned short o[8] = {0, 0, 0, 0, 0, 0, 0, 0};
                if (gr < M) {
                    const float4* ap = (const float4*)(A + (size_t)gr * K + kof);
                    float4 v0 = ap[0], v1 = ap[1];
                    o[0] = f2h(v0.x); o[1] = f2h(v0.y); o[2] = f2h(v0.z); o[3] = f2h(v0.w);
                    o[4] = f2h(v1.x); o[5] = f2h(v1.y); o[6] = f2h(v1.z); o[7] = f2h(v1.w);
                }
                *(uint4*)(&As[rr * LDK + u * 8]) = *(uint4*)o;
            } else {
                const unsigned short* A = (const unsigned short*)Aptr;
                uint4 v = make_uint4(0, 0, 0, 0);
                if (gr < M) v = *(const uint4*)(A + (size_t)gr * K + kof);
                *(uint4*)(&As[rr * LDK + u * 8]) = v;
            }
        }
#pragma unroll
        for (int br = r0; br < BN; br += 32) {
            uint4 v = *(const uint4*)(Bt + (size_t)br * K + kof);
            *(uint4*)(&Bs[br * LDK + u * 8]) = v;
        }
        __syncthreads();

        short8 af[2][2];
#pragma unroll
        for (int rt = 0; rt < 2; rt++)
#pragma unroll
            for (int kt = 0; kt < 2; kt++)
                af[rt][kt] = *(const short8*)(&As[(w * 32 + rt * 16 + col) * LDK + kt * 32 + q * 8]);
#pragma unroll
        for (int kt = 0; kt < 2; kt++)
#pragma unroll
            for (int ct = 0; ct < NCT; ct++) {
                short8 bf = *(const short8*)(&Bs[(ct * 16 + col) * LDK + kt * 32 + q * 8]);
#pragma unroll
                for (int rt = 0; rt < 2; rt++)
                    acc[rt][ct] = __builtin_amdgcn_mfma_f32_16x16x32_f16(
                        af[rt][kt], bf, acc[rt][ct], 0, 0, 0);
            }
        __syncthreads();
    }

    float swv[NCT], dwv[NCT];
#pragma unroll
    for (int ct = 0; ct < NCT; ct++) {
        int c = ct * 16 + col;
        swv[ct] = as_[c];
        dwv[ct] = ad_[c];
    }
#pragma unroll
    for (int rt = 0; rt < 2; rt++) {
#pragma unroll
        for (int r = 0; r < 4; r++) {
            int gr = rowBase + w * 32 + rt * 16 + q * 4 + r;
            if constexpr (H == 4) {
                float ps[4] = {0, 0, 0, 0}, pd[4] = {0, 0, 0, 0};
#pragma unroll
                for (int ct = 0; ct < NCT; ct++) {
                    float v = acc[rt][ct][r];
                    ps[ct >> 1] += v * swv[ct];
                    pd[ct >> 1] += v * dwv[ct];
                }
#pragma unroll
                for (int m = 1; m < 16; m <<= 1)
#pragma unroll
                    for (int h = 0; h < 4; h++) {
                        ps[h] += __shfl_xor(ps[h], m);
                        pd[h] += __shfl_xor(pd[h], m);
                    }
                if (gr < M) {
#pragma unroll
                    for (int ct = 0; ct < NCT; ct++)
                        hb[(size_t)gr * BN + ct * 16 + col] = f2h(acc[rt][ct][r]);
                    if (col == 0) {
                        *(float4*)(a_s + (size_t)gr * 4) = make_float4(ps[0], ps[1], ps[2], ps[3]);
                        *(float4*)(a_d + (size_t)gr * 4) = make_float4(pd[0], pd[1], pd[2], pd[3]);
                    }
                }
            } else {
                float ps = 0.f, pd = 0.f;
#pragma unroll
                for (int ct = 0; ct < NCT; ct++) {
                    float v = acc[rt][ct][r];
                    ps += v * swv[ct];
                    pd += v * dwv[ct];
                }
#pragma unroll
                for (int m = 1; m < 16; m <<= 1) {
                    ps += __shfl_xor(ps, m);
                    pd += __shfl_xor(pd, m);
                }
                if (gr < M) {
#pragma unroll
                    for (int ct = 0; ct < NCT; ct++)
                        hb[(size_t)gr * BN + ct * 16 + col] = f2h(acc[rt][ct][r]);
                    if (col == 0) { a_s[gr] = ps; a_d[gr] = pd; }
                }
            }
        }
    }
}

// -------- 4-nodes-per-wave: softmax + aggregate(f16 h, pk_fma) + bias + LN + ELU --------
__global__ __launch_bounds__(256) void k_aggregate_ln(
    const unsigned short* __restrict__ hb, const float* __restrict__ a_src,
    const float* __restrict__ a_dst, const int* __restrict__ row_ptr,
    const int* __restrict__ esrc, const float* __restrict__ bias,
    const float* __restrict__ gamma, const float* __restrict__ beta,
    unsigned short* __restrict__ xb) {
    __shared__ uint2 slab_all[4][4 * 4 * DCAPP];  // [wave][node][head][j]
    int tid = threadIdx.x;
    int w = tid >> 6, lane = tid & 63;
    int g = lane >> 4, i = lane & 15;
    int myhead = i >> 2;
    uint2* slab = slab_all[w];
    int n0 = blockIdx.x * 16 + w * 4;
    int n = n0 + g;
    bool valid = n < NN;
    int start = 0, deg = 0;
    if (valid) {
        start = row_ptr[n];
        int end = (n == NN - 1) ? ETOT : row_ptr[n + 1];
        deg = end - start;
    }
    int wmax = deg;
#pragma unroll
    for (int m = 1; m < 64; m <<= 1) wmax = max(wmax, __shfl_xor(wmax, m));

    if (wmax <= DCAP) {
        float4 ad = make_float4(0.f, 0.f, 0.f, 0.f);
        if (valid) ad = ((const float4*)a_dst)[n];
        float d0 = 0.f, d1 = 0.f, d2 = 0.f, d3 = 0.f;
        uint2* nslab = slab + g * (4 * DCAPP);
        for (int k = i; k < deg; k += 16) {
            int s = esrc[start + k];
            float4 a = ((const float4*)a_src)[s];
            float e0 = a.x + ad.x; e0 = fmaxf(e0, SLOPE * e0); float x0 = __expf(e0);
            float e1 = a.y + ad.y; e1 = fmaxf(e1, SLOPE * e1); float x1 = __expf(e1);
            float e2 = a.z + ad.z; e2 = fmaxf(e2, SLOPE * e2); float x2 = __expf(e2);
            float e3 = a.w + ad.w; e3 = fmaxf(e3, SLOPE * e3); float x3 = __expf(e3);
            nslab[0 * DCAPP + k] = make_uint2((unsigned)s, __float_as_uint(x0));
            nslab[1 * DCAPP + k] = make_uint2((unsigned)s, __float_as_uint(x1));
            nslab[2 * DCAPP + k] = make_uint2((unsigned)s, __float_as_uint(x2));
            nslab[3 * DCAPP + k] = make_uint2((unsigned)s, __float_as_uint(x3));
            d0 += x0; d1 += x1; d2 += x2; d3 += x3;
        }
#pragma unroll
        for (int m = 1; m < 16; m <<= 1) {
            d0 += __shfl_xor(d0, m);
            d1 += __shfl_xor(d1, m);
            d2 += __shfl_xor(d2, m);
            d3 += __shfl_xor(d3, m);
        }
        float dh = myhead == 0 ? d0 : myhead == 1 ? d1 : myhead == 2 ? d2 : d3;
        float inv = 1.f / (dh + 1e-16f);
        wave_lds_fence();

        __half2 acc2[4];
#pragma unroll
        for (int k = 0; k < 4; k++) acc2[k] = __float2half2_rn(0.f);
        const uint2* myrow = nslab + myhead * DCAPP;
        const unsigned short* hbase = hb + i * 8;
        int j = 0;
        for (; j + 4 <= deg; j += 4) {
            uint2 p0 = myrow[j], p1 = myrow[j + 1], p2 = myrow[j + 2], p3 = myrow[j + 3];
            uint4 u0 = *(const uint4*)(hbase + (size_t)p0.x * 128);
            uint4 u1 = *(const uint4*)(hbase + (size_t)p1.x * 128);
            uint4 u2 = *(const uint4*)(hbase + (size_t)p2.x * 128);
            uint4 u3 = *(const uint4*)(hbase + (size_t)p3.x * 128);
            pk8(acc2, u0, __float2half2_rn(__uint_as_float(p0.y)));
            pk8(acc2, u1, __float2half2_rn(__uint_as_float(p1.y)));
            pk8(acc2, u2, __float2half2_rn(__uint_as_float(p2.y)));
            pk8(acc2, u3, __float2half2_rn(__uint_as_float(p3.y)));
        }
        for (; j < deg; j++) {
            uint2 p = myrow[j];
            uint4 uu = *(const uint4*)(hbase + (size_t)p.x * 128);
            pk8(acc2, uu, __float2half2_rn(__uint_as_float(p.y)));
        }
        float acc[8];
#pragma unroll
        for (int k = 0; k < 4; k++) {
            float2 f = __half22float2(acc2[k]);
            acc[2 * k] = f.x * inv;
            acc[2 * k + 1] = f.y * inv;
        }

        if (valid) {
            float y[8];
            float sum = 0.f;
            const float4* bp = (const float4*)(bias + i * 8);
            float4 b0 = bp[0], b1 = bp[1];
#pragma unroll
            for (int k = 0; k < 8; k++) {
                float b = k < 4 ? (&b0.x)[k] : (&b1.x)[k - 4];
                y[k] = acc[k] + b;
                sum += y[k];
            }
#pragma unroll
            for (int m = 1; m < 16; m <<= 1) sum += __shfl_xor(sum, m);
            float mu = sum * (1.f / 128.f);
            float ss = 0.f;
            float d[8];
#pragma unroll
            for (int k = 0; k < 8; k++) { d[k] = y[k] - mu; ss += d[k] * d[k]; }
#pragma unroll
            for (int m = 1; m < 16; m <<= 1) ss += __shfl_xor(ss, m);
            float is = rsqrtf(ss * (1.f / 128.f) + 1e-5f);
            const float4* gp = (const float4*)(gamma + i * 8);
            const float4* ep = (const float4*)(beta + i * 8);
            float4 g0 = gp[0], g1 = gp[1], e0 = ep[0], e1 = ep[1];
            unsigned short o16[8];
#pragma unroll
            for (int k = 0; k < 8; k++) {
                float gm = k < 4 ? (&g0.x)[k] : (&g1.x)[k - 4];
                float bt = k < 4 ? (&e0.x)[k] : (&e1.x)[k - 4];
                float z = gm * (d[k] * is) + bt;
                o16[k] = f2h(z > 0.f ? z : __expf(z) - 1.f);
            }
            *(uint4*)(xb + (size_t)n * 128 + i * 8) = *(uint4*)o16;
        }
    } else {
        // cold path (~never): full-wave sequential, f32 accumulate
        for (int m4 = 0; m4 < 4; m4++) {
            int nm = n0 + m4;
            if (nm >= NN) continue;
            int startm = row_ptr[nm];
            int endm = (nm == NN - 1) ? ETOT : row_ptr[nm + 1];
            int degm = endm - startm;
            float4 ad = ((const float4*)a_dst)[nm];
            int gg = lane >> 4, c16 = lane & 15, hh = c16 >> 2;
            float acc[8];
#pragma unroll
            for (int k = 0; k < 8; k++) acc[k] = 0.f;
            if (degm <= 64) {
                int msrc = 0;
                float me0 = 0.f, me1 = 0.f, me2 = 0.f, me3 = 0.f;
                if (lane < degm) {
                    int s = esrc[startm + lane];
                    msrc = s;
                    float4 a = ((const float4*)a_src)[s];
                    float e0 = a.x + ad.x; e0 = fmaxf(e0, SLOPE * e0); me0 = __expf(e0);
                    float e1 = a.y + ad.y; e1 = fmaxf(e1, SLOPE * e1); me1 = __expf(e1);
                    float e2 = a.z + ad.z; e2 = fmaxf(e2, SLOPE * e2); me2 = __expf(e2);
                    float e3 = a.w + ad.w; e3 = fmaxf(e3, SLOPE * e3); me3 = __expf(e3);
                }
                float d0 = me0, d1 = me1, d2 = me2, d3 = me3;
#pragma unroll
                for (int m = 1; m < 64; m <<= 1) {
                    d0 += __shfl_xor(d0, m);
                    d1 += __shfl_xor(d1, m);
                    d2 += __shfl_xor(d2, m);
                    d3 += __shfl_xor(d3, m);
                }
                me0 *= 1.f / (d0 + 1e-16f);
                me1 *= 1.f / (d1 + 1e-16f);
                me2 *= 1.f / (d2 + 1e-16f);
                me3 *= 1.f / (d3 + 1e-16f);
                int iters = (degm + 3) >> 2;
                for (int it = 0; it < iters; it++) {
                    int j = gg + (it << 2);
                    int jj = j < degm ? j : 0;
                    int s = __shfl(msrc, jj);
                    float a0 = __shfl(me0, jj), a1 = __shfl(me1, jj);
                    float a2 = __shfl(me2, jj), a3 = __shfl(me3, jj);
                    if (j < degm) {
                        float al = hh == 0 ? a0 : hh == 1 ? a1 : hh == 2 ? a2 : a3;
                        uint4 uu = *(const uint4*)(hb + (size_t)s * 128 + c16 * 8);
                        fma8f(acc, uu, al);
                    }
                }
            } else {
                float d0 = 0.f, d1 = 0.f, d2 = 0.f, d3 = 0.f;
                for (int k = startm + lane; k < endm; k += 64) {
                    int s = esrc[k];
                    float4 a = ((const float4*)a_src)[s];
                    float e0 = a.x + ad.x; e0 = fmaxf(e0, SLOPE * e0); d0 += __expf(e0);
                    float e1 = a.y + ad.y; e1 = fmaxf(e1, SLOPE * e1); d1 += __expf(e1);
                    float e2 = a.z + ad.z; e2 = fmaxf(e2, SLOPE * e2); d2 += __expf(e2);
                    float e3 = a.w + ad.w; e3 = fmaxf(e3, SLOPE * e3); d3 += __expf(e3);
                }
#pragma unroll
                for (int m = 1; m < 64; m <<= 1) {
                    d0 += __shfl_xor(d0, m);
                    d1 += __shfl_xor(d1, m);
                    d2 += __shfl_xor(d2, m);
                    d3 += __shfl_xor(d3, m);
                }
                float invh = hh == 0 ? 1.f / (d0 + 1e-16f) : hh == 1 ? 1.f / (d1 + 1e-16f)
                           : hh == 2 ? 1.f / (d2 + 1e-16f) : 1.f / (d3 + 1e-16f);
                float adh = hh == 0 ? ad.x : hh == 1 ? ad.y : hh == 2 ? ad.z : ad.w;
                for (int j = gg; j < degm; j += 4) {
                    int s = esrc[startm + j];
                    float e = a_src[(size_t)s * 4 + hh] + adh;
                    e = fmaxf(e, SLOPE * e);
                    float al = __expf(e) * invh;
                    uint4 uu = *(const uint4*)(hb + (size_t)s * 128 + c16 * 8);
                    fma8f(acc, uu, al);
                }
            }
#pragma unroll
            for (int k = 0; k < 8; k++) {
                acc[k] += __shfl_xor(acc[k], 16);
                acc[k] += __shfl_xor(acc[k], 32);
            }
            if (lane < 16) {
                float y[8];
                float sum = 0.f;
                const float4* bp = (const float4*)(bias + lane * 8);
                float4 b0 = bp[0], b1 = bp[1];
#pragma unroll
                for (int k = 0; k < 8; k++) {
                    float b = k < 4 ? (&b0.x)[k] : (&b1.x)[k - 4];
                    y[k] = acc[k] + b;
                    sum += y[k];
                }
#pragma unroll
                for (int m = 1; m < 16; m <<= 1) sum += __shfl_xor(sum, m);
                float mu = sum * (1.f / 128.f);
                float ss = 0.f;
                float d[8];
#pragma unroll
                for (int k = 0; k < 8; k++) { d[k] = y[k] - mu; ss += d[k] * d[k]; }
#pragma unroll
                for (int m = 1; m < 16; m <<= 1) ss += __shfl_xor(ss, m);
                float is = rsqrtf(ss * (1.f / 128.f) + 1e-5f);
                const float4* gp = (const float4*)(gamma + lane * 8);
                const float4* ep = (const float4*)(beta + lane * 8);
                float4 g0 = gp[0], g1 = gp[1], e0 = ep[0], e1 = ep[1];
                unsigned short o16[8];
#pragma unroll
                for (int k = 0; k < 8; k++) {
                    float gm = k < 4 ? (&g0.x)[k] : (&g1.x)[k - 4];
                    float bt = k < 4 ? (&e0.x)[k] : (&e1.x)[k - 4];
                    float z = gm * (d[k] * is) + bt;
                    o16[k] = f2h(z > 0.f ? z : __expf(z) - 1.f);
                }
                *(uint4*)(xb + (size_t)nm * 128 + lane * 8) = *(uint4*)o16;
            }
        }
    }
}

// -------- final layer, wave-per-node: H=1, C=32 (f16 h), writes fp32 d_out --------
__global__ __launch_bounds__(256) void k_agg_final(
    const unsigned short* __restrict__ hb, const float* __restrict__ a_src,
    const float* __restrict__ a_dst, const int* __restrict__ row_ptr,
    const int* __restrict__ esrc, const float* __restrict__ bf,
    float* __restrict__ out) {
    __shared__ uint2 slab_all[4][64];
    int lane = threadIdx.x & 63;
    int w = threadIdx.x >> 6;
    uint2* slab = slab_all[w];
    int n = blockIdx.x * 4 + w;
    if (n >= NN) return;
    int start = row_ptr[n];
    int end = (n == NN - 1) ? ETOT : row_ptr[n + 1];
    int deg = end - start;
    float adn = a_dst[n];

    int g = lane >> 3, c8 = lane & 7;
    float acc[4] = {0.f, 0.f, 0.f, 0.f};

    if (deg <= 64) {
        int msrc = 0;
        float me = 0.f;
        if (lane < deg) {
            int s = esrc[start + lane];
            msrc = s;
            float e = a_src[s] + adn;
            e = fmaxf(e, SLOPE * e);
            me = __expf(e);
        }
        float d = me;
#pragma unroll
        for (int m = 1; m < 64; m <<= 1) d += __shfl_xor(d, m);
        float inv = 1.f / (d + 1e-16f);
        if (lane < deg) slab[lane] = make_uint2((unsigned)msrc, __float_as_uint(me));
        wave_lds_fence();
        __half2 acc2[2] = {__float2half2_rn(0.f), __float2half2_rn(0.f)};
        const unsigned short* hbase = hb + c8 * 4;
        int j = g;
        for (; j + 8 < deg; j += 16) {
            uint2 p0 = slab[j], p1 = slab[j + 8];
            uint2 u0 = *(const uint2*)(hbase + (size_t)p0.x * 32);
            uint2 u1 = *(const uint2*)(hbase + (size_t)p1.x * 32);
            __half2 a0 = __float2half2_rn(__uint_as_float(p0.y));
            __half2 a1 = __float2half2_rn(__uint_as_float(p1.y));
            acc2[0] = __hfma2(*(__half2*)&u0.x, a0, acc2[0]);
            acc2[1] = __hfma2(*(__half2*)&u0.y, a0, acc2[1]);
            acc2[0] = __hfma2(*(__half2*)&u1.x, a1, acc2[0]);
            acc2[1] = __hfma2(*(__half2*)&u1.y, a1, acc2[1]);
        }
        if (j < deg) {
            uint2 p = slab[j];
            uint2 u = *(const uint2*)(hbase + (size_t)p.x * 32);
            __half2 a2 = __float2half2_rn(__uint_as_float(p.y));
            acc2[0] = __hfma2(*(__half2*)&u.x, a2, acc2[0]);
            acc2[1] = __hfma2(*(__half2*)&u.y, a2, acc2[1]);
        }
        float2 f0 = __half22float2(acc2[0]);
        float2 f1 = __half22float2(acc2[1]);
        acc[0] = f0.x * inv; acc[1] = f0.y * inv;
        acc[2] = f1.x * inv; acc[3] = f1.y * inv;
    } else {
        float d = 0.f;
        for (int k = start + lane; k < end; k += 64) {
            int s = esrc[k];
            float e = a_src[s] + adn;
            e = fmaxf(e, SLOPE * e);
            d += __expf(e);
        }
#pragma unroll
        for (int m = 1; m < 64; m <<= 1) d += __shfl_xor(d, m);
        float inv = 1.f / (d + 1e-16f);
        for (int j = g; j < deg; j += 8) {
            int s = esrc[start + j];
            float e = a_src[s] + adn;
            e = fmaxf(e, SLOPE * e);
            float al = __expf(e) * inv;
            uint2 u = *(const uint2*)(hb + (size_t)s * 32 + c8 * 4);
            acc[0] += h_lo(u.x) * al; acc[1] += h_hi(u.x) * al;
            acc[2] += h_lo(u.y) * al; acc[3] += h_hi(u.y) * al;
        }
    }
#pragma unroll
    for (int k = 0; k < 4; k++) {
        acc[k] += __shfl_xor(acc[k], 8);
        acc[k] += __shfl_xor(acc[k], 16);
        acc[k] += __shfl_xor(acc[k], 32);
    }
    if (lane < 8) {
        float4 b4 = ((const float4*)bf)[lane];
        float4 o = make_float4(acc[0] + b4.x, acc[1] + b4.y, acc[2] + b4.z,
                               acc[3] + b4.w);
        ((float4*)out)[(size_t)n * 8 + lane] = o;
    }
}

// ---------------- launch ----------------
extern "C" void kernel_launch(void* const* d_in, const int* in_sizes, int n_in,
                              void* d_out, int out_size, void* d_ws,
                              size_t ws_size, hipStream_t stream) {
    const float* x  = (const float*)d_in[0];
    const int* ei   = (const int*)d_in[1];
    const float* W[3]  = {(const float*)d_in[2], (const float*)d_in[8],  (const float*)d_in[14]};
    const float* AS[3] = {(const float*)d_in[3], (const float*)d_in[9],  (const float*)d_in[15]};
    const float* AD[3] = {(const float*)d_in[4], (const float*)d_in[10], (const float*)d_in[16]};
    const float* Bb[3] = {(const float*)d_in[5], (const float*)d_in[11], (const float*)d_in[17]};
    const float* G[3]  = {(const float*)d_in[6], (const float*)d_in[12], (const float*)d_in[18]};
    const float* BE[3] = {(const float*)d_in[7], (const float*)d_in[13], (const float*)d_in[19]};
    const float* Wf  = (const float*)d_in[20];
    const float* asf = (const float*)d_in[21];
    const float* adf = (const float*)d_in[22];
    const float* bfp = (const float*)d_in[23];
    float* out = (float*)d_out;

    unsigned short* xb = (unsigned short*)d_ws;          // NN*128 f16 (agg outputs)
    unsigned short* hb = xb + (size_t)NN * 128;          // NN*128 f16
    float* a_s = (float*)(hb + (size_t)NN * 128);
    float* a_d = a_s + (size_t)NN * 4;
    int* row_ptr = (int*)(a_d + (size_t)NN * 4);
    int* esrc    = row_ptr + NN;
    int* gbh     = esrc + ETOT;
    int* ebase   = gbh + NB;
    int* gcur    = ebase + NB + 1;
    int* pbuf    = gcur + NB;                            // EE ints
    unsigned short* Wt0 = (unsigned short*)(pbuf + EE);  // 128*64
    unsigned short* Wt1 = Wt0 + 128 * 64;                // 128*128
    unsigned short* Wt2 = Wt1 + 128 * 128;               // 128*128
    unsigned short* Wtf = Wt2 + 128 * 128;               // 32*128

    // weights conversion (single launch)
    k_cvt_w4<<<(45056 + 255) / 256, 256, 0, stream>>>(W[0], W[1], W[2], Wf,
                                                      Wt0, Wt1, Wt2, Wtf);

    // CSR build (gbh zeroed via graph-safe async memset)
    hipMemsetAsync(gbh, 0, NB * sizeof(int), stream);
    k_bhist<<<(EE + 2047) / 2048, 256, 0, stream>>>(ei, gbh);
    k_bscan<<<1, 128, 0, stream>>>(gbh, ebase, gcur);
    k_bscatter<<<(EE + CCH - 1) / CCH, 256, 0, stream>>>(ei, gcur, pbuf);
    k_bcsr<<<NB, 256, 0, stream>>>(pbuf, ebase, row_ptr, esrc);

    // layers (layer 0 reads fp32 x directly)
    int gblk = (NN + 127) / 128;
    k_mfma_att<128, 4, true><<<gblk, 256, 0, stream>>>(x, Wt0, AS[0], AD[0],
                                                       hb, a_s, a_d, NN, 64);
    k_aggregate_ln<<<(NN + 15) / 16, 256, 0, stream>>>(hb, a_s, a_d, row_ptr,
                                                       esrc, Bb[0], G[0], BE[0], xb);
    const unsigned short* Wts[2] = {Wt1, Wt2};
    for (int l = 1; l < 3; l++) {
        k_mfma_att<128, 4, false><<<gblk, 256, 0, stream>>>(xb, Wts[l - 1], AS[l], AD[l],
                                                            hb, a_s, a_d, NN, 128);
        k_aggregate_ln<<<(NN + 15) / 16, 256, 0, stream>>>(hb, a_s, a_d, row_ptr,
                                                           esrc, Bb[l], G[l], BE[l], xb);
    }
    k_mfma_att<32, 1, false><<<gblk, 256, 0, stream>>>(xb, Wtf, asf, adf, hb, a_s, a_d,
                                                       NN, 128);
    k_agg_final<<<(NN + 3) / 4, 256, 0, stream>>>(hb, a_s, a_d, row_ptr, esrc,
                                                  bfp, out);
}